// Round 14
// baseline (568.813 us; speedup 1.0000x reference)
//
#include <hip/hip_runtime.h>
#include <math.h>

#define TT 10
#define BB 32
#define CIN 3
#define COUT 64
#define HH 64
#define WW 64
#define HW (HH*WW)           // 4096
#define DECAY 0.2f
#define INH 1.625f

typedef __attribute__((ext_vector_type(2))) float f32x2;

__device__ __forceinline__ unsigned int enc_f(float f) {
    unsigned int u = __float_as_uint(f);
    return (u & 0x80000000u) ? ~u : (u | 0x80000000u);
}
__device__ __forceinline__ float dec_f(unsigned int u) {
    u = (u & 0x80000000u) ? (u & 0x7FFFFFFFu) : ~u;
    return __uint_as_float(u);
}

// Packed f32 FMA (VGPR weight pair). v_pk_fma_f32 is IEEE fma per 32b lane.
// NOTE: VOP3P sources must be VGPRs — SGPR operands are ILLEGAL here (r13
// compile failure). Scalar weights go through plain fmaf -> v_fma_f32 (VOP3,
// 1 SGPR source allowed).
__device__ __forceinline__ void pkfma_lo(f32x2& acc, f32x2 w2, f32x2 x2) {
    asm("v_pk_fma_f32 %0, %1, %2, %0 op_sel:[0,0,0] op_sel_hi:[0,1,1]"
        : "+v"(acc) : "v"(w2), "v"(x2));
}
__device__ __forceinline__ void pkfma_hi(f32x2& acc, f32x2 w2, f32x2 x2) {
    asm("v_pk_fma_f32 %0, %1, %2, %0 op_sel:[1,0,0] op_sel_hi:[1,1,1]"
        : "+v"(acc) : "v"(w2), "v"(x2));
}

// full-wave fmax reduce on the VALU pipe (DPP), no LDS traffic.
// row_ror 1,2,4,8 -> each lane = its row-of-16 max; bcast15+bcast31 ->
// lane 63 = global max. max is order-independent -> bit-exact.
#define DPP_FMAX(V, CTRL) {                                                   \
    int o_ = __builtin_amdgcn_update_dpp(__float_as_int(V), __float_as_int(V),\
                                         (CTRL), 0xf, 0xf, false);            \
    V = fmaxf(V, __int_as_float(o_)); }
__device__ __forceinline__ float wave_fmax(float v) {
    DPP_FMAX(v, 0x121); DPP_FMAX(v, 0x122); DPP_FMAX(v, 0x124);
    DPP_FMAX(v, 0x128); DPP_FMAX(v, 0x142); DPP_FMAX(v, 0x143);
    return v;   // lane 63 holds the wave max
}

#define CONV_TAP(ACC, FI, X2) { if ((FI) & 1) pkfma_hi(ACC, wp[(FI)>>1], X2); \
                                else          pkfma_lo(ACC, wp[(FI)>>1], X2); }

// fused's broadcast CKH (unchanged from r12)
#define CKH(RP, FB)                                                           \
    {                                                                         \
        const float* rpf_ = (const float*)(RP);                              \
        float4 q0_ = *(const float4*)(rpf_ + 0);                              \
        float4 q1_ = *(const float4*)(rpf_ + 4);                              \
        float4 q2_ = *(const float4*)(rpf_ + 8);                              \
        float4 q3_ = *(const float4*)(rpf_ + 12);                             \
        float4 q4_ = *(const float4*)(rpf_ + 16);                             \
        f32x2 d0 = {q0_.x, q0_.y}, d1 = {q0_.z, q0_.w},                       \
              d2 = {q1_.x, q1_.y}, d3 = {q1_.z, q1_.w},                       \
              d4 = {q2_.x, q2_.y}, d5 = {q2_.z, q2_.w},                       \
              d6 = {q3_.x, q3_.y}, d7 = {q3_.z, q3_.w},                       \
              d8 = {q4_.x, q4_.y}, d9 = {q4_.z, q4_.w};                       \
        CONV_TAP(a0, (FB)+0, d0); CONV_TAP(a0, (FB)+1, d1); CONV_TAP(a0, (FB)+2, d2); \
        CONV_TAP(a1, (FB)+0, d1); CONV_TAP(a1, (FB)+1, d2); CONV_TAP(a1, (FB)+2, d3); \
        CONV_TAP(a2, (FB)+0, d2); CONV_TAP(a2, (FB)+1, d3); CONV_TAP(a2, (FB)+2, d4); \
        CONV_TAP(a3, (FB)+0, d3); CONV_TAP(a3, (FB)+1, d4); CONV_TAP(a3, (FB)+2, d5); \
        CONV_TAP(a4, (FB)+0, d4); CONV_TAP(a4, (FB)+1, d5); CONV_TAP(a4, (FB)+2, d6); \
        CONV_TAP(a5, (FB)+0, d5); CONV_TAP(a5, (FB)+1, d6); CONV_TAP(a5, (FB)+2, d7); \
        CONV_TAP(a6, (FB)+0, d6); CONV_TAP(a6, (FB)+1, d7); CONV_TAP(a6, (FB)+2, d8); \
        CONV_TAP(a7, (FB)+0, d7); CONV_TAP(a7, (FB)+1, d8); CONV_TAP(a7, (FB)+2, d9); \
    }

#define LOAD_WP                                                               \
    f32x2 wp[14];                                                             \
    {                                                                         \
        const float* wl = Wt + lane * 27;                                     \
        _Pragma("unroll")                                                     \
        for (int k = 0; k < 13; k++) { f32x2 t_; t_.x = wl[2*k]; t_.y = wl[2*k+1]; wp[k] = t_; } \
        { f32x2 t_; t_.x = wl[26]; t_.y = wl[26]; wp[13] = t_; }              \
    }

// ---------------------------------------------------------------------------
// Pass 1: threshold max + interleaved zero-fill, LANE = PIXEL.
// r12 diagnosis: broadcast LDS reads are bytes-throughput bound (b128 costs
// 2x b64 cycles -> same B/cyc; ~72us of LDS-pipe per kernel). Here each
// lane loads ITS OWN 27 t-paired taps once (27 ds_read_b64, unique addrs)
// and loops the 64 channels with wave-uniform weights in SGPRs: plain
// fmaf(wl[k], tap, acc) -> v_fma_f32 vdst, s, v, v (legal VOP3, r13 lesson:
// VOP3P cannot take SGPRs). LDS delivery drops ~96%; conv VALU doubles vs
// packed but lands ~29us — net win if the LDS model is right.
// Per-channel max over pixels = DPP wave reduce (VALU pipe, no LDS).
// FMA order per output (ci,kh asc; w0,w1,w2; t-paired) identical to r12 ->
// bit-identical i. Grid (16 rowgroups, B, 5 t-pairs) x 256.
// Plain __launch_bounds__(256): no occupancy hint (spill lesson).
// ---------------------------------------------------------------------------
__global__ __launch_bounds__(256) void thr_kernel(
    const float* __restrict__ x,        // (T,B,3,64,64)
    const float* __restrict__ Wt,       // (64,3,3,3)
    unsigned int* __restrict__ thr_raw, // (T,64) pre-zeroed
    float* __restrict__ out)            // (T,B,64,64,64) — zero-filled here
{
    __shared__ f32x2 sx[CIN][6][68];    // t-pair interleaved, 9.8 KB
    __shared__ f32x2 wmaxL[4][COUT];    // per-row, per-channel max pair

    const int tid  = threadIdx.x;
    const int lane = tid & 63;          // PIXEL
    const int wave = tid >> 6;          // row within 4-row group
    const int h0   = blockIdx.x * 4;
    const int b    = blockIdx.y;
    const int t0   = blockIdx.z * 2;    // even timestep of the pair

    // stage x tile for BOTH t (3ci x 6r x 66c pairs), coalesced, zero-padded
    const float* xb0 = x + ((size_t)t0 * BB + b) * (CIN * HW);
    const float* xb1 = xb0 + (size_t)BB * CIN * HW;
    for (int l = tid; l < CIN * 6 * 66; l += 256) {
        int ci  = l / 396;
        int r   = (l % 396) / 66;
        int col = l % 66;
        int gh = h0 + r - 1;
        int gw = col - 1;
        f32x2 v; v.x = 0.f; v.y = 0.f;
        if (gh >= 0 && gh < HH && gw >= 0 && gw < WW) {
            size_t off = (size_t)ci * HW + gh * WW + gw;
            v.x = xb0[off];
            v.y = xb1[off];
        }
        sx[ci][r][col] = v;
    }
    __syncthreads();   // only LDS staging waits here

    // ---- per-lane taps, loaded ONCE, reused by all 64 channels ----
    // col (lane+kw) holds x[gw = lane-1+kw] -> taps at kw=-1,0,+1 of px lane
    f32x2 tp_[CIN][3][3];
    #pragma unroll
    for (int ci = 0; ci < CIN; ci++)
        #pragma unroll
        for (int kh = 0; kh < 3; kh++)
            #pragma unroll
            for (int kw = 0; kw < 3; kw++)
                tp_[ci][kh][kw] = sx[ci][wave + kh][lane + kw];

    float* ob0 = out + (((size_t)t0 * BB + b) * COUT) * HW;
    float* ob1 = ob0 + (size_t)BB * COUT * HW;

    #pragma unroll 2
    for (int c = 0; c < COUT; c++) {
        // interleaved zero-fill: 32 float4/thread spread over c=0..31
        // (2 t-slabs = 128KB/block); drains under conv, final barrier waits
        if (c < 32) {
            int l   = c * 256 + tid;   // 0..8191 float4s
            int th  = l >> 12;
            int row = (l >> 4) & 255;  // (cch<<2)|hr
            int q   = l & 15;
            int cch = row >> 2;
            int hr  = row & 3;
            float* ob = th ? ob1 : ob0;
            *(float4*)(ob + (size_t)cch * HW + (h0 + hr) * WW + q * 4) =
                make_float4(0.f, 0.f, 0.f, 0.f);
        }

        const float* wl = Wt + c * 27;  // uniform address -> s_load -> SGPR
        float ax = 0.f, ay = 0.f;
        #pragma unroll
        for (int ci = 0; ci < CIN; ci++)
            #pragma unroll
            for (int kh = 0; kh < 3; kh++)
                #pragma unroll
                for (int kw = 0; kw < 3; kw++) {
                    float ws = wl[ci * 9 + kh * 3 + kw];
                    f32x2 tv = tp_[ci][kh][kw];
                    ax = fmaf(ws, tv.x, ax);    // v_fma_f32 v,s,v,v
                    ay = fmaf(ws, tv.y, ay);
                }

        // wave max over pixels for this channel, both t (DPP, no LDS)
        float g0 = wave_fmax(ax);
        float g1 = wave_fmax(ay);
        int b0 = __builtin_amdgcn_readlane(__float_as_int(g0), 63);
        int b1 = __builtin_amdgcn_readlane(__float_as_int(g1), 63);
        if (lane == 0) {
            f32x2 g; g.x = __int_as_float(b0); g.y = __int_as_float(b1);
            wmaxL[wave][c] = g;
        }
    }

    __syncthreads();   // drains the interleaved fill too (hidden under conv)
    if (wave < 2) {    // wave 0 reduces t0, wave 1 reduces t1 (parallel)
        f32x2 m0 = wmaxL[0][lane], m1 = wmaxL[1][lane],
              m2 = wmaxL[2][lane], m3 = wmaxL[3][lane];
        float m = (wave == 0)
                ? fmaxf(fmaxf(m0.x, m1.x), fmaxf(m2.x, m3.x))
                : fmaxf(fmaxf(m0.y, m1.y), fmaxf(m2.y, m3.y));
        atomicMax(&thr_raw[(t0 + wave) * COUT + lane], enc_f(m));
    }
}

// ---------------------------------------------------------------------------
// Pass 2: fused conv + LIF — UNCHANGED from r12 (current best, passing).
// ---------------------------------------------------------------------------
__global__ __launch_bounds__(256) void fused_kernel(
    const float* __restrict__ x,              // (T,B,3,64,64)
    const float* __restrict__ Wt,             // (64,3,3,3)
    const unsigned int* __restrict__ thr_raw, // (T,64)
    float* __restrict__ out)                  // (T,B,64,64,64) pre-zeroed
{
    __shared__ f32x2 sx[5][CIN][3][36];       // 12,960 B, t-pair interleaved

    const int tid  = threadIdx.x;
    const int lane = tid & 63;                            // channel
    const int wave = tid >> 6;
    const int p0   = __builtin_amdgcn_readfirstlane(wave * 8);  // local px base
    const int b    = blockIdx.x >> 7;
    const int h    = (blockIdx.x >> 1) & 63;
    const int w0   = (blockIdx.x & 1) << 5;               // half-row start

    LOAD_WP

    // ---- stage all 5 t-pairs: rows h-1..h+1, cols w0-1..w0+32 ----
    {
        const float* xb0 = x + (size_t)b * (CIN * HW);
        const size_t ts = (size_t)BB * CIN * HW;
        for (int l = tid; l < 5 * 306; l += 256) {        // 306 = 3*3*34
            int tp  = l / 306;
            int r0  = l - tp * 306;
            int ci  = r0 / 102;
            int r1  = r0 - ci * 102;
            int r   = r1 / 34;
            int col = r1 - r * 34;
            int gh = h + r - 1;
            int gw = w0 + col - 1;
            f32x2 v; v.x = 0.f; v.y = 0.f;
            if (gh >= 0 && gh < HH && gw >= 0 && gw < WW) {
                size_t off = (size_t)ci * HW + gh * WW + gw;
                v.x = xb0[(size_t)(2 * tp)     * ts + off];
                v.y = xb0[(size_t)(2 * tp + 1) * ts + off];
            }
            sx[tp][ci][r][col] = v;
        }
    }

    float mem[8];
    #pragma unroll
    for (int j = 0; j < 8; j++) mem[j] = 0.f;

    __syncthreads();   // the only barrier in this kernel

#define LIF_M(J, V) {                                                      \
        float cur = fmaxf(V, 0.f);                                         \
        float z   = (cur - s04) * sinv;                                    \
        float sig = 1.0f / (1.0f + expf(-z));                              \
        mv[J] = mem[J] * DECAY + thr * sig;                                \
        spor |= (mv[J] > thr) ? 1 : 0;                                     \
    }
#define LIF_W(J) {                                                         \
        float m   = mv[J];                                                 \
        int   sp  = m > thr;                                               \
        float score = sp ? m : 0.f;                                        \
        unsigned long long blt = __ballot(sp);                             \
        int fr = 0, sp_any = 0;                                            \
        if (blt) {                                                         \
            float bs = score;                                              \
            int   bc = lane;                                               \
            _Pragma("unroll")                                              \
            for (int off = 32; off > 0; off >>= 1) {                       \
                float so = __shfl_xor(bs, off, 64);                        \
                int   co = __shfl_xor(bc, off, 64);                        \
                if (so > bs || (so == bs && co < bc)) { bs = so; bc = co; }\
            }                                                              \
            int spw = __shfl(sp, bc, 64);   /* winner's spike = any_sp */  \
            fr     = (lane == bc) && sp;                                   \
            sp_any = spw;                                                  \
        }                                                                  \
        mem[J] = fr ? 0.f : (m - (sp_any ? sinh_ : 0.f));                  \
        if (fr) fmask |= (1 << (J));                                       \
    }
#define LIF_T(TIDX, F)                                                     \
    {                                                                      \
        float thr   = dec_f(F) + 1e-4f;                                    \
        float sinv  = 8.0f / thr;                                          \
        float s04   = 0.4f * thr;                                          \
        float sinh_ = INH * thr;                                           \
        int spor = 0;                                                      \
        float mv[8];                                                       \
        LIF_M(0, a0.SEL); LIF_M(1, a1.SEL); LIF_M(2, a2.SEL); LIF_M(3, a3.SEL); \
        LIF_M(4, a4.SEL); LIF_M(5, a5.SEL); LIF_M(6, a6.SEL); LIF_M(7, a7.SEL); \
        if (__ballot(spor)) {   /* rare: some pixel spiked in this wave */ \
            int fmask = 0;                                                 \
            LIF_W(0); LIF_W(1); LIF_W(2); LIF_W(3);                        \
            LIF_W(4); LIF_W(5); LIF_W(6); LIF_W(7);                        \
            if (fmask) {                                                   \
                float* os = out + (((size_t)(TIDX) * BB + b) * COUT) * HW  \
                          + h * WW + w0;                                   \
                _Pragma("unroll")                                          \
                for (int j = 0; j < 8; j++)                                \
                    if (fmask & (1 << j))                                  \
                        os[(size_t)lane * HW + p0 + j] = 1.0f;             \
            }                                                              \
        } else {                                                           \
            _Pragma("unroll")                                              \
            for (int j = 0; j < 8; j++) mem[j] = mv[j];                    \
        }                                                                  \
    }

    #pragma unroll 1
    for (int tp = 0; tp < 5; tp++) {
        unsigned int tru0 = thr_raw[(2 * tp)     * COUT + lane];
        unsigned int tru1 = thr_raw[(2 * tp + 1) * COUT + lane];

        f32x2 a0={0.f,0.f},a1={0.f,0.f},a2={0.f,0.f},a3={0.f,0.f},
              a4={0.f,0.f},a5={0.f,0.f},a6={0.f,0.f},a7={0.f,0.f};
        #pragma unroll
        for (int ci = 0; ci < CIN; ci++)
            #pragma unroll
            for (int kh = 0; kh < 3; kh++)
                CKH(&sx[tp][ci][kh][p0], ci * 9 + kh * 3);

#define SEL x
        LIF_T(2 * tp, tru0)
#undef SEL
#define SEL y
        LIF_T(2 * tp + 1, tru1)
#undef SEL
    }
#undef LIF_T
#undef LIF_W
#undef LIF_M
}

// ---------------------------------------------------------------------------
extern "C" void kernel_launch(void* const* d_in, const int* in_sizes, int n_in,
                              void* d_out, int out_size, void* d_ws, size_t ws_size,
                              hipStream_t stream) {
    const float* x = (const float*)d_in[0];   // (T,B,3,64,64)
    const float* W = (const float*)d_in[1];   // (64,3,3,3)
    float* out     = (float*)d_out;           // (T,B,64,64,64)

    unsigned int* thr = (unsigned int*)d_ws;  // (T,64) — only 2.5 KB of ws used
    hipMemsetAsync(thr, 0, TT * COUT * sizeof(unsigned int), stream);

    thr_kernel<<<dim3(HH / 4, BB, TT / 2), 256, 0, stream>>>(x, W, thr, out);
    fused_kernel<<<dim3(BB * HH * 2), 256, 0, stream>>>(x, W, thr, out);
}

// Round 15
// 490.510 us; speedup vs baseline: 1.1596x; 1.1596x over previous
//
#include <hip/hip_runtime.h>
#include <math.h>

#define TT 10
#define BB 32
#define CIN 3
#define COUT 64
#define HH 64
#define WW 64
#define HW (HH*WW)           // 4096
#define DECAY 0.2f
#define INH 1.625f

typedef __attribute__((ext_vector_type(2))) float f32x2;

__device__ __forceinline__ unsigned int enc_f(float f) {
    unsigned int u = __float_as_uint(f);
    return (u & 0x80000000u) ? ~u : (u | 0x80000000u);
}
__device__ __forceinline__ float dec_f(unsigned int u) {
    u = (u & 0x80000000u) ? (u & 0x7FFFFFFFu) : ~u;
    return __uint_as_float(u);
}

// Packed f32 FMA, broadcasting one half of the weight pair to both lanes.
// v_pk_fma_f32 is IEEE fma per 32b lane -> bit-identical to scalar fmaf.
// (VOP3P sources must be VGPRs — SGPR weight operand was r13's compile fail.)
__device__ __forceinline__ void pkfma_lo(f32x2& acc, f32x2 w2, f32x2 x2) {
    asm("v_pk_fma_f32 %0, %1, %2, %0 op_sel:[0,0,0] op_sel_hi:[0,1,1]"
        : "+v"(acc) : "v"(w2), "v"(x2));
}
__device__ __forceinline__ void pkfma_hi(f32x2& acc, f32x2 w2, f32x2 x2) {
    asm("v_pk_fma_f32 %0, %1, %2, %0 op_sel:[1,0,0] op_sel_hi:[1,1,1]"
        : "+v"(acc) : "v"(w2), "v"(x2));
}
#define CONV_TAP(ACC, FI, X2) { if ((FI) & 1) pkfma_hi(ACC, wp[(FI)>>1], X2); \
                                else          pkfma_lo(ACC, wp[(FI)>>1], X2); }

// One (ci,kh) slice: five b128 broadcast reads feed 24 pk_fma (= 48 FMAs:
// 8 px x 3 taps x 2 timesteps). d-values and per-acc tap order (w0,w1,w2;
// ci,kh ascending) identical to r11/r12 -> bit-identical i.
#define CKH(RP, FB)                                                           \
    {                                                                         \
        const float* rpf_ = (const float*)(RP);                              \
        float4 q0_ = *(const float4*)(rpf_ + 0);                              \
        float4 q1_ = *(const float4*)(rpf_ + 4);                              \
        float4 q2_ = *(const float4*)(rpf_ + 8);                              \
        float4 q3_ = *(const float4*)(rpf_ + 12);                             \
        float4 q4_ = *(const float4*)(rpf_ + 16);                             \
        f32x2 d0 = {q0_.x, q0_.y}, d1 = {q0_.z, q0_.w},                       \
              d2 = {q1_.x, q1_.y}, d3 = {q1_.z, q1_.w},                       \
              d4 = {q2_.x, q2_.y}, d5 = {q2_.z, q2_.w},                       \
              d6 = {q3_.x, q3_.y}, d7 = {q3_.z, q3_.w},                       \
              d8 = {q4_.x, q4_.y}, d9 = {q4_.z, q4_.w};                       \
        CONV_TAP(a0, (FB)+0, d0); CONV_TAP(a0, (FB)+1, d1); CONV_TAP(a0, (FB)+2, d2); \
        CONV_TAP(a1, (FB)+0, d1); CONV_TAP(a1, (FB)+1, d2); CONV_TAP(a1, (FB)+2, d3); \
        CONV_TAP(a2, (FB)+0, d2); CONV_TAP(a2, (FB)+1, d3); CONV_TAP(a2, (FB)+2, d4); \
        CONV_TAP(a3, (FB)+0, d3); CONV_TAP(a3, (FB)+1, d4); CONV_TAP(a3, (FB)+2, d5); \
        CONV_TAP(a4, (FB)+0, d4); CONV_TAP(a4, (FB)+1, d5); CONV_TAP(a4, (FB)+2, d6); \
        CONV_TAP(a5, (FB)+0, d5); CONV_TAP(a5, (FB)+1, d6); CONV_TAP(a5, (FB)+2, d7); \
        CONV_TAP(a6, (FB)+0, d6); CONV_TAP(a6, (FB)+1, d7); CONV_TAP(a6, (FB)+2, d8); \
        CONV_TAP(a7, (FB)+0, d7); CONV_TAP(a7, (FB)+1, d8); CONV_TAP(a7, (FB)+2, d9); \
    }

#define LOAD_WP                                                               \
    f32x2 wp[14];                                                             \
    {                                                                         \
        const float* wl = Wt + lane * 27;                                     \
        _Pragma("unroll")                                                     \
        for (int k = 0; k < 13; k++) { f32x2 t_; t_.x = wl[2*k]; t_.y = wl[2*k+1]; wp[k] = t_; } \
        { f32x2 t_; t_.x = wl[26]; t_.y = wl[26]; wp[13] = t_; }              \
    }

// ---------------------------------------------------------------------------
// Pass 1: threshold max + interleaved zero-fill, two timesteps per block
// (t-pair packed conv). EXACT r12 structure (best measured, 493.5us) except
// the fill addressing: with m = 4*cc+k the r12 store target decomposes as
//   addr(m) = ob[m>>4] + BASE(tid) + (m&15)*4*HW,
//   BASE = (tid>>6)*HW + (h0+((tid>>4)&3))*WW + (tid&15)*4
// (q and hr are tid-constant; c = 4*(m&15) + (tid>>6)). Same 32 addresses,
// same values, ~6 fewer VALU per store. Grid (16 rowgroups, B, 5 t-pairs).
// Plain __launch_bounds__(256): no occupancy hint (r2-r4/r9 spill lesson).
// ---------------------------------------------------------------------------
__global__ __launch_bounds__(256) void thr_kernel(
    const float* __restrict__ x,        // (T,B,3,64,64)
    const float* __restrict__ Wt,       // (64,3,3,3)
    unsigned int* __restrict__ thr_raw, // (T,64) pre-zeroed
    float* __restrict__ out)            // (T,B,64,64,64) — zero-filled here
{
    __shared__ f32x2 sx[CIN][6][68];    // t-pair interleaved, 9.8 KB
    __shared__ float wmax[4][2][COUT];

    const int tid  = threadIdx.x;
    const int lane = tid & 63;          // channel
    const int wave = tid >> 6;          // row within 4-row group
    const int h0   = blockIdx.x * 4;
    const int b    = blockIdx.y;
    const int t0   = blockIdx.z * 2;    // even timestep of the pair

    LOAD_WP

    // stage x tile for BOTH t (3ci x 6r x 66c pairs), coalesced, zero-padded
    const float* xb0 = x + ((size_t)t0 * BB + b) * (CIN * HW);
    const float* xb1 = xb0 + (size_t)BB * CIN * HW;
    for (int l = tid; l < CIN * 6 * 66; l += 256) {
        int ci  = l / 396;
        int r   = (l % 396) / 66;
        int col = l % 66;
        int gh = h0 + r - 1;
        int gw = col - 1;
        f32x2 v; v.x = 0.f; v.y = 0.f;
        if (gh >= 0 && gh < HH && gw >= 0 && gw < WW) {
            size_t off = (size_t)ci * HW + gh * WW + gw;
            v.x = xb0[off];
            v.y = xb1[off];
        }
        sx[ci][r][col] = v;
    }
    __syncthreads();   // only LDS staging waits here

    // precomputed fill pointers (derivation in header comment)
    float* f0 = out + (((size_t)t0 * BB + b) * COUT) * HW
              + (tid >> 6) * HW + (h0 + ((tid >> 4) & 3)) * WW + (tid & 15) * 4;
    float* f1 = f0 + (size_t)BB * COUT * HW;

    float mx0 = -INFINITY, mx1 = -INFINITY;

    for (int cc = 0; cc < 8; cc++) {           // 8-pixel chunks along the row
        // interleaved zero-fill: 4 float4/thread/chunk (2 t-slabs = 128KB);
        // compile-time offsets after unroll; drains under the conv below
        #pragma unroll
        for (int k = 0; k < 4; k++) {
            int m = cc * 4 + k;                // 0..31, compile-time
            float* fp = ((m & 16) ? f1 : f0) + (size_t)(m & 15) * (4 * HW);
            *(float4*)fp = make_float4(0.f, 0.f, 0.f, 0.f);
        }

        f32x2 a0={0.f,0.f},a1={0.f,0.f},a2={0.f,0.f},a3={0.f,0.f},
              a4={0.f,0.f},a5={0.f,0.f},a6={0.f,0.f},a7={0.f,0.f};
        #pragma unroll
        for (int ci = 0; ci < CIN; ci++)
            #pragma unroll
            for (int kh = 0; kh < 3; kh++)
                CKH(&sx[ci][wave + kh][cc * 8], ci * 9 + kh * 3);

        // max is order-independent -> tree form is bit-identical
        mx0 = fmaxf(mx0, fmaxf(fmaxf(fmaxf(a0.x,a1.x),fmaxf(a2.x,a3.x)),
                               fmaxf(fmaxf(a4.x,a5.x),fmaxf(a6.x,a7.x))));
        mx1 = fmaxf(mx1, fmaxf(fmaxf(fmaxf(a0.y,a1.y),fmaxf(a2.y,a3.y)),
                               fmaxf(fmaxf(a4.y,a5.y),fmaxf(a6.y,a7.y))));
    }

    wmax[wave][0][lane] = mx0;
    wmax[wave][1][lane] = mx1;
    __syncthreads();   // drains the interleaved fill too (hidden under conv)
    if (wave < 2) {    // wave 0 reduces t0, wave 1 reduces t1 (parallel)
        float m = fmaxf(fmaxf(wmax[0][wave][lane], wmax[1][wave][lane]),
                        fmaxf(wmax[2][wave][lane], wmax[3][wave][lane]));
        atomicMax(&thr_raw[(t0 + wave) * COUT + lane], enc_f(m));
    }
}

// ---------------------------------------------------------------------------
// Pass 2: fused conv + LIF — EXACT r12 version (best measured, passing).
// Half-row blocks, t-pair packed conv, branchless LIF fast path.
// ---------------------------------------------------------------------------
__global__ __launch_bounds__(256) void fused_kernel(
    const float* __restrict__ x,              // (T,B,3,64,64)
    const float* __restrict__ Wt,             // (64,3,3,3)
    const unsigned int* __restrict__ thr_raw, // (T,64)
    float* __restrict__ out)                  // (T,B,64,64,64) pre-zeroed
{
    __shared__ f32x2 sx[5][CIN][3][36];       // 12,960 B, t-pair interleaved

    const int tid  = threadIdx.x;
    const int lane = tid & 63;                            // channel
    const int wave = tid >> 6;
    const int p0   = __builtin_amdgcn_readfirstlane(wave * 8);  // local px base
    const int b    = blockIdx.x >> 7;
    const int h    = (blockIdx.x >> 1) & 63;
    const int w0   = (blockIdx.x & 1) << 5;               // half-row start

    LOAD_WP

    // ---- stage all 5 t-pairs: rows h-1..h+1, cols w0-1..w0+32 ----
    {
        const float* xb0 = x + (size_t)b * (CIN * HW);
        const size_t ts = (size_t)BB * CIN * HW;
        for (int l = tid; l < 5 * 306; l += 256) {        // 306 = 3*3*34
            int tp  = l / 306;
            int r0  = l - tp * 306;
            int ci  = r0 / 102;
            int r1  = r0 - ci * 102;
            int r   = r1 / 34;
            int col = r1 - r * 34;
            int gh = h + r - 1;
            int gw = w0 + col - 1;
            f32x2 v; v.x = 0.f; v.y = 0.f;
            if (gh >= 0 && gh < HH && gw >= 0 && gw < WW) {
                size_t off = (size_t)ci * HW + gh * WW + gw;
                v.x = xb0[(size_t)(2 * tp)     * ts + off];
                v.y = xb0[(size_t)(2 * tp + 1) * ts + off];
            }
            sx[tp][ci][r][col] = v;
        }
    }

    float mem[8];
    #pragma unroll
    for (int j = 0; j < 8; j++) mem[j] = 0.f;

    __syncthreads();   // the only barrier in this kernel

#define LIF_M(J, V) {                                                      \
        float cur = fmaxf(V, 0.f);                                         \
        float z   = (cur - s04) * sinv;                                    \
        float sig = 1.0f / (1.0f + expf(-z));                              \
        mv[J] = mem[J] * DECAY + thr * sig;                                \
        spor |= (mv[J] > thr) ? 1 : 0;                                     \
    }
#define LIF_W(J) {                                                         \
        float m   = mv[J];                                                 \
        int   sp  = m > thr;                                               \
        float score = sp ? m : 0.f;                                        \
        unsigned long long blt = __ballot(sp);                             \
        int fr = 0, sp_any = 0;                                            \
        if (blt) {                                                         \
            float bs = score;                                              \
            int   bc = lane;                                               \
            _Pragma("unroll")                                              \
            for (int off = 32; off > 0; off >>= 1) {                       \
                float so = __shfl_xor(bs, off, 64);                        \
                int   co = __shfl_xor(bc, off, 64);                        \
                if (so > bs || (so == bs && co < bc)) { bs = so; bc = co; }\
            }                                                              \
            int spw = __shfl(sp, bc, 64);   /* winner's spike = any_sp */  \
            fr     = (lane == bc) && sp;                                   \
            sp_any = spw;                                                  \
        }                                                                  \
        mem[J] = fr ? 0.f : (m - (sp_any ? sinh_ : 0.f));                  \
        if (fr) fmask |= (1 << (J));                                       \
    }
#define LIF_T(TIDX, F)                                                     \
    {                                                                      \
        float thr   = dec_f(F) + 1e-4f;                                    \
        float sinv  = 8.0f / thr;                                          \
        float s04   = 0.4f * thr;                                          \
        float sinh_ = INH * thr;                                           \
        int spor = 0;                                                      \
        float mv[8];                                                       \
        LIF_M(0, a0.SEL); LIF_M(1, a1.SEL); LIF_M(2, a2.SEL); LIF_M(3, a3.SEL); \
        LIF_M(4, a4.SEL); LIF_M(5, a5.SEL); LIF_M(6, a6.SEL); LIF_M(7, a7.SEL); \
        if (__ballot(spor)) {   /* rare: some pixel spiked in this wave */ \
            int fmask = 0;                                                 \
            LIF_W(0); LIF_W(1); LIF_W(2); LIF_W(3);                        \
            LIF_W(4); LIF_W(5); LIF_W(6); LIF_W(7);                        \
            if (fmask) {                                                   \
                float* os = out + (((size_t)(TIDX) * BB + b) * COUT) * HW  \
                          + h * WW + w0;                                   \
                _Pragma("unroll")                                          \
                for (int j = 0; j < 8; j++)                                \
                    if (fmask & (1 << j))                                  \
                        os[(size_t)lane * HW + p0 + j] = 1.0f;             \
            }                                                              \
        } else {                                                           \
            _Pragma("unroll")                                              \
            for (int j = 0; j < 8; j++) mem[j] = mv[j];                    \
        }                                                                  \
    }

    #pragma unroll 1
    for (int tp = 0; tp < 5; tp++) {
        unsigned int tru0 = thr_raw[(2 * tp)     * COUT + lane];
        unsigned int tru1 = thr_raw[(2 * tp + 1) * COUT + lane];

        f32x2 a0={0.f,0.f},a1={0.f,0.f},a2={0.f,0.f},a3={0.f,0.f},
              a4={0.f,0.f},a5={0.f,0.f},a6={0.f,0.f},a7={0.f,0.f};
        #pragma unroll
        for (int ci = 0; ci < CIN; ci++)
            #pragma unroll
            for (int kh = 0; kh < 3; kh++)
                CKH(&sx[tp][ci][kh][p0], ci * 9 + kh * 3);

#define SEL x
        LIF_T(2 * tp, tru0)
#undef SEL
#define SEL y
        LIF_T(2 * tp + 1, tru1)
#undef SEL
    }
#undef LIF_T
#undef LIF_W
#undef LIF_M
}

// ---------------------------------------------------------------------------
extern "C" void kernel_launch(void* const* d_in, const int* in_sizes, int n_in,
                              void* d_out, int out_size, void* d_ws, size_t ws_size,
                              hipStream_t stream) {
    const float* x = (const float*)d_in[0];   // (T,B,3,64,64)
    const float* W = (const float*)d_in[1];   // (64,3,3,3)
    float* out     = (float*)d_out;           // (T,B,64,64,64)

    unsigned int* thr = (unsigned int*)d_ws;  // (T,64) — only 2.5 KB of ws used
    hipMemsetAsync(thr, 0, TT * COUT * sizeof(unsigned int), stream);

    thr_kernel<<<dim3(HH / 4, BB, TT / 2), 256, 0, stream>>>(x, W, thr, out);
    fused_kernel<<<dim3(BB * HH * 2), 256, 0, stream>>>(x, W, thr, out);
}